// Round 1
// baseline (562.223 us; speedup 1.0000x reference)
//
#include <hip/hip_runtime.h>

// Problem constants (match reference setup_inputs)
constexpr int CN0 = 1000000;   // x rows
constexpr int CN1 = 300000;    // stem conv output rows
constexpr int CN2 = 80000;     // pooled rows
constexpr int CN3 = 30000;     // downsampled rows
constexpr float BN_EPS = 1e-5f;

__device__ __forceinline__ void fma4(float4& a, float s, const float4& b) {
  a.x = fmaf(s, b.x, a.x);
  a.y = fmaf(s, b.y, a.y);
  a.z = fmaf(s, b.z, a.z);
  a.w = fmaf(s, b.w, a.w);
}

__device__ __forceinline__ float2 bn_ab(float s, float q, float invn, float gamma, float beta) {
  float m = s * invn;
  float v = fmaf(q, invn, -m * m);
  float rstd = rsqrtf(v + BN_EPS);
  float a = gamma * rstd;
  float b = beta - m * a;
  return make_float2(a, b);
}

// ---------------------------------------------------------------------------
// Stem conv: y1[N1][64] = gather(x, neigh) @ W  (K = 27*4 = 108 held entirely
// in LDS). Block tile: 64 nodes x 64 outs, 256 threads, 4x4 microtile.
// Also accumulates per-channel sum / sumsq into stats[0..63] / stats[64..127].
// ---------------------------------------------------------------------------
__global__ __launch_bounds__(256) void k_stem(
    const float* __restrict__ x, const int* __restrict__ neigh,
    const float* __restrict__ W, float* __restrict__ y1,
    float* __restrict__ stats) {
  constexpr int APAD = 116;  // row pitch in floats (16B-aligned, bank-friendly)
  __shared__ __align__(16) float Alds[64 * APAD];
  __shared__ __align__(16) float Blds[108 * 64];
  const int tid = threadIdx.x;
  const int n0 = blockIdx.x * 64;

  // Stage B: linear copy of W [108][64] = 1728 float4
  {
    const float4* Wf4 = (const float4*)W;
    float4* Bf4 = (float4*)Blds;
    for (int e = tid; e < 1728; e += 256) Bf4[e] = Wf4[e];
  }
  // Stage A: 64 nodes x 27 gathered float4 rows of x
  for (int j = 0; j < 7; ++j) {
    int g = tid + j * 256;
    if (g < 64 * 27) {
      int i = g / 27, k = g % 27;
      float4 v = make_float4(0.f, 0.f, 0.f, 0.f);
      int row = n0 + i;
      if (row < CN1) {
        int idx = neigh[row * 27 + k];
        v = *(const float4*)(x + idx * 4);
      }
      *(float4*)&Alds[i * APAD + k * 4] = v;
    }
  }
  __syncthreads();

  const int tc = tid & 15;  // out-channel group (x4)
  const int tn = tid >> 4;  // node group (x4)
  float4 acc[4];
#pragma unroll
  for (int r = 0; r < 4; ++r) acc[r] = make_float4(0.f, 0.f, 0.f, 0.f);

#pragma unroll 3
  for (int kk4 = 0; kk4 < 27; ++kk4) {
    float4 a[4], b[4];
#pragma unroll
    for (int r = 0; r < 4; ++r)
      a[r] = *(const float4*)&Alds[(tn * 4 + r) * APAD + kk4 * 4];
#pragma unroll
    for (int q = 0; q < 4; ++q)
      b[q] = *(const float4*)&Blds[(kk4 * 4 + q) * 64 + tc * 4];
#pragma unroll
    for (int r = 0; r < 4; ++r) {
      fma4(acc[r], a[r].x, b[0]);
      fma4(acc[r], a[r].y, b[1]);
      fma4(acc[r], a[r].z, b[2]);
      fma4(acc[r], a[r].w, b[3]);
    }
  }

  // Store outputs
#pragma unroll
  for (int r = 0; r < 4; ++r) {
    int row = n0 + tn * 4 + r;
    if (row < CN1) *(float4*)&y1[row * 64 + tc * 4] = acc[r];
  }

  // Per-block stats reduction (invalid rows contributed acc==0)
  __syncthreads();  // done reading Alds; reuse as scratch
  float sx = 0, sy = 0, sz = 0, sw = 0, qx = 0, qy = 0, qz = 0, qw = 0;
#pragma unroll
  for (int r = 0; r < 4; ++r) {
    sx += acc[r].x; qx += acc[r].x * acc[r].x;
    sy += acc[r].y; qy += acc[r].y * acc[r].y;
    sz += acc[r].z; qz += acc[r].z * acc[r].z;
    sw += acc[r].w; qw += acc[r].w * acc[r].w;
  }
  float* S = Alds;
  float* Q = Alds + 16 * 64;
  S[tn * 64 + tc * 4 + 0] = sx; Q[tn * 64 + tc * 4 + 0] = qx;
  S[tn * 64 + tc * 4 + 1] = sy; Q[tn * 64 + tc * 4 + 1] = qy;
  S[tn * 64 + tc * 4 + 2] = sz; Q[tn * 64 + tc * 4 + 2] = qz;
  S[tn * 64 + tc * 4 + 3] = sw; Q[tn * 64 + tc * 4 + 3] = qw;
  __syncthreads();
  if (tid < 64) {
    float ss = 0.f, qq = 0.f;
#pragma unroll
    for (int t2 = 0; t2 < 16; ++t2) {
      ss += S[t2 * 64 + tid];
      qq += Q[t2 * 64 + tid];
    }
    atomicAdd(&stats[tid], ss);
    atomicAdd(&stats[64 + tid], qq);
  }
}

// ---------------------------------------------------------------------------
// Pool: h2[n][c] = relu(max_j BN(y1[child[n][j]][c])), using monotone-affine
// rewrite (a>0 -> use max, a<0 -> use min). One wave per node.
// ---------------------------------------------------------------------------
__global__ __launch_bounds__(256) void k_pool(
    const float* __restrict__ y1, const int* __restrict__ child,
    const float* __restrict__ stats, const float* __restrict__ gamma,
    const float* __restrict__ beta, float* __restrict__ h2) {
  const int tid = threadIdx.x;
  const int lane = tid & 63;
  const int n = blockIdx.x * 4 + (tid >> 6);
  float2 ab = bn_ab(stats[lane], stats[64 + lane], 1.0f / CN1, gamma[lane],
                    beta[lane]);
  float mx = -INFINITY, mn = INFINITY;
  const int* crow = child + n * 8;
#pragma unroll
  for (int j = 0; j < 8; ++j) {
    int ch = crow[j];
    float v = y1[ch * 64 + lane];
    mx = fmaxf(mx, v);
    mn = fminf(mn, v);
  }
  float t = (ab.x > 0.f) ? fmaf(ab.x, mx, ab.y) : fmaf(ab.x, mn, ab.y);
  h2[n * 64 + lane] = fmaxf(t, 0.f);
}

// ---------------------------------------------------------------------------
// Gathered GEMM for the 64-channel convs. src[M'][64] gathered via
// neigh[M][27], weights Wa (and Wb when DUAL, concatenated as channels
// 64..127). Writes out[M][OUTC] and per-channel sum/sumsq stats[2*OUTC].
// ---------------------------------------------------------------------------
template <int OUTC, bool DUAL>
__global__ __launch_bounds__(256) void k_conv(
    const float* __restrict__ src, const int* __restrict__ neigh,
    const float* __restrict__ Wa, const float* __restrict__ Wb,
    float* __restrict__ out, float* __restrict__ stats, int M) {
  constexpr int TC = OUTC / 4;   // thread cols (16 or 32)
  constexpr int TN = 256 / TC;   // thread rows (16 or 8)
  constexpr int TM = TN * 4;     // node tile (64 or 32)
  constexpr int APAD = 68;
  constexpr int TPN = 256 / TM;   // staging threads per node (4 or 8)
  constexpr int F4PT = 16 / TPN;  // float4s per staging thread (4 or 2)
  __shared__ __align__(16) float Alds[TM * APAD];
  __shared__ __align__(16) float Blds[64 * OUTC];

  const int tid = threadIdx.x;
  const int n0 = blockIdx.x * TM;
  const int tc = tid % TC;
  const int tn = tid / TC;
  const int si = tid / TPN;  // staging node in tile
  const int sp = tid % TPN;  // staging part
  const int srow = n0 + si;

  float4 acc[4];
#pragma unroll
  for (int r = 0; r < 4; ++r) acc[r] = make_float4(0.f, 0.f, 0.f, 0.f);

  for (int k = 0; k < 27; ++k) {
    // Stage A: gather TM rows of src (64 floats each)
    int idx = (srow < M) ? neigh[srow * 27 + k] : -1;
#pragma unroll
    for (int j = 0; j < F4PT; ++j) {
      int f4 = sp * F4PT + j;  // 0..15 within row
      float4 v = make_float4(0.f, 0.f, 0.f, 0.f);
      if (idx >= 0) v = *(const float4*)(src + idx * 64 + f4 * 4);
      *(float4*)&Alds[si * APAD + f4 * 4] = v;
    }
    // Stage B: W[k] as [64][OUTC]
    if (DUAL) {
#pragma unroll
      for (int j = 0; j < (64 * OUTC / 4) / 256; ++j) {
        int e4 = tid + j * 256;
        int ci = e4 / TC;
        int c = (e4 % TC) * 4;
        const float* s2 = (c < 64) ? (Wa + (k * 64 + ci) * 64 + c)
                                   : (Wb + (k * 64 + ci) * 64 + (c - 64));
        ((float4*)Blds)[e4] = *(const float4*)s2;
      }
    } else {
      const float4* Wf4 = (const float4*)(Wa + k * 64 * 64);
#pragma unroll
      for (int j = 0; j < (64 * OUTC / 4) / 256; ++j) {
        int e4 = tid + j * 256;
        ((float4*)Blds)[e4] = Wf4[e4];
      }
    }
    __syncthreads();
#pragma unroll 4
    for (int kk4 = 0; kk4 < 16; ++kk4) {
      float4 a[4], b[4];
#pragma unroll
      for (int r = 0; r < 4; ++r)
        a[r] = *(const float4*)&Alds[(tn * 4 + r) * APAD + kk4 * 4];
#pragma unroll
      for (int q = 0; q < 4; ++q)
        b[q] = *(const float4*)&Blds[(kk4 * 4 + q) * OUTC + tc * 4];
#pragma unroll
      for (int r = 0; r < 4; ++r) {
        fma4(acc[r], a[r].x, b[0]);
        fma4(acc[r], a[r].y, b[1]);
        fma4(acc[r], a[r].z, b[2]);
        fma4(acc[r], a[r].w, b[3]);
      }
    }
    __syncthreads();
  }

  // Store
#pragma unroll
  for (int r = 0; r < 4; ++r) {
    int row = n0 + tn * 4 + r;
    if (row < M) *(float4*)&out[row * OUTC + tc * 4] = acc[r];
  }

  // Stats (Alds reused as scratch; last __syncthreads in loop protects reads)
  float sx = 0, sy = 0, sz = 0, sw = 0, qx = 0, qy = 0, qz = 0, qw = 0;
#pragma unroll
  for (int r = 0; r < 4; ++r) {
    sx += acc[r].x; qx += acc[r].x * acc[r].x;
    sy += acc[r].y; qy += acc[r].y * acc[r].y;
    sz += acc[r].z; qz += acc[r].z * acc[r].z;
    sw += acc[r].w; qw += acc[r].w * acc[r].w;
  }
  float* S = Alds;
  float* Q = Alds + TN * OUTC;
  S[tn * OUTC + tc * 4 + 0] = sx; Q[tn * OUTC + tc * 4 + 0] = qx;
  S[tn * OUTC + tc * 4 + 1] = sy; Q[tn * OUTC + tc * 4 + 1] = qy;
  S[tn * OUTC + tc * 4 + 2] = sz; Q[tn * OUTC + tc * 4 + 2] = qz;
  S[tn * OUTC + tc * 4 + 3] = sw; Q[tn * OUTC + tc * 4 + 3] = qw;
  __syncthreads();
  for (int c = tid; c < OUTC; c += 256) {
    float ss = 0.f, qq = 0.f;
#pragma unroll
    for (int t2 = 0; t2 < TN; ++t2) {
      ss += S[t2 * OUTC + c];
      qq += Q[t2 * OUTC + c];
    }
    atomicAdd(&stats[c], ss);
    atomicAdd(&stats[OUTC + c], qq);
  }
}

// ---------------------------------------------------------------------------
// BN+ReLU on y2d channels 0..63 -> out1 (materialize res-block intermediate)
// ---------------------------------------------------------------------------
__global__ __launch_bounds__(256) void k_bnrelu(
    const float* __restrict__ y2d, const float* __restrict__ stats,
    const float* __restrict__ gamma, const float* __restrict__ beta,
    float* __restrict__ out1) {
  int e = blockIdx.x * 256 + threadIdx.x;  // over N3*64 (exact)
  int i = e >> 6, c = e & 63;
  float2 ab =
      bn_ab(stats[c], stats[128 + c], 1.0f / CN3, gamma[c], beta[c]);
  out1[e] = fmaxf(fmaf(ab.x, y2d[i * 128 + c], ab.y), 0.f);
}

// ---------------------------------------------------------------------------
// Final: relu(BN2(y3) + BNd(y2d[:,64:128]))
// ---------------------------------------------------------------------------
__global__ __launch_bounds__(256) void k_final(
    const float* __restrict__ y3, const float* __restrict__ y2d,
    const float* __restrict__ stats2, const float* __restrict__ stats1d,
    const float* __restrict__ g2, const float* __restrict__ b2,
    const float* __restrict__ gd, const float* __restrict__ bd,
    float* __restrict__ dout) {
  int e = blockIdx.x * 256 + threadIdx.x;  // over N3*64 (exact)
  int i = e >> 6, c = e & 63;
  float2 ab2 = bn_ab(stats2[c], stats2[64 + c], 1.0f / CN3, g2[c], b2[c]);
  float2 abd =
      bn_ab(stats1d[64 + c], stats1d[192 + c], 1.0f / CN3, gd[c], bd[c]);
  float o = fmaf(ab2.x, y3[e], ab2.y) + fmaf(abd.x, y2d[i * 128 + 64 + c], abd.y);
  dout[e] = fmaxf(o, 0.f);
}

// ---------------------------------------------------------------------------
extern "C" void kernel_launch(void* const* d_in, const int* in_sizes, int n_in,
                              void* d_out, int out_size, void* d_ws,
                              size_t ws_size, hipStream_t stream) {
  const float* x = (const float*)d_in[0];
  const int* neigh_stem = (const int*)d_in[1];
  const int* pool_child = (const int*)d_in[2];
  const int* neigh_ds = (const int*)d_in[3];
  const int* neigh_res = (const int*)d_in[4];
  const float* W_stem = (const float*)d_in[5];
  const float* g_stem = (const float*)d_in[6];
  const float* b_stem = (const float*)d_in[7];
  const float* W1 = (const float*)d_in[8];
  const float* g1 = (const float*)d_in[9];
  const float* b1 = (const float*)d_in[10];
  const float* W2 = (const float*)d_in[11];
  const float* g2 = (const float*)d_in[12];
  const float* b2 = (const float*)d_in[13];
  const float* Wd = (const float*)d_in[14];
  const float* gd = (const float*)d_in[15];
  const float* bd = (const float*)d_in[16];
  float* out = (float*)d_out;
  float* ws = (float*)d_ws;

  // Workspace layout (floats). y1 region is reused for y2d/out1/y3 after pool.
  float* y1 = ws;                    // N1*64 = 19,200,000
  float* h2 = ws + 19200000;         // N2*64 =  5,120,000
  float* y2d = ws;                   // N3*128 = 3,840,000 (reuses y1)
  float* out1 = ws + 3840000;        // N3*64  = 1,920,000
  float* y3 = ws + 5760000;          // N3*64  = 1,920,000
  float* stats = ws + 24320000;      // 512 floats
  float* stats_stem = stats;         // [128]
  float* stats_1d = stats + 128;     // [256]  (sums[128], sumsq[128])
  float* stats_2 = stats + 384;      // [128]

  hipMemsetAsync(stats, 0, 512 * sizeof(float), stream);

  k_stem<<<(CN1 + 63) / 64, 256, 0, stream>>>(x, neigh_stem, W_stem, y1,
                                              stats_stem);
  k_pool<<<CN2 / 4, 256, 0, stream>>>(y1, pool_child, stats_stem, g_stem,
                                      b_stem, h2);
  k_conv<128, true><<<(CN3 + 31) / 32, 256, 0, stream>>>(
      h2, neigh_ds, W1, Wd, y2d, stats_1d, CN3);
  k_bnrelu<<<CN3 * 64 / 256, 256, 0, stream>>>(y2d, stats_1d, g1, b1, out1);
  k_conv<64, false><<<(CN3 + 63) / 64, 256, 0, stream>>>(
      out1, neigh_res, W2, nullptr, y3, stats_2, CN3);
  k_final<<<CN3 * 64 / 256, 256, 0, stream>>>(y3, y2d, stats_2, stats_1d, g2,
                                              b2, gd, bd, out);
}

// Round 2
// 379.067 us; speedup vs baseline: 1.4832x; 1.4832x over previous
//
#include <hip/hip_runtime.h>

// Problem constants (match reference setup_inputs)
constexpr int CN0 = 1000000;   // x rows
constexpr int CN1 = 300000;    // stem conv output rows
constexpr int CN2 = 80000;     // pooled rows
constexpr int CN3 = 30000;     // downsampled rows
constexpr float BN_EPS = 1e-5f;

typedef __attribute__((ext_vector_type(8))) short bf16x8;
typedef __attribute__((ext_vector_type(4))) float f32x4;

__device__ __forceinline__ void fma4(float4& a, float s, const float4& b) {
  a.x = fmaf(s, b.x, a.x);
  a.y = fmaf(s, b.y, a.y);
  a.z = fmaf(s, b.z, a.z);
  a.w = fmaf(s, b.w, a.w);
}

__device__ __forceinline__ float2 bn_ab(float s, float q, float invn, float gamma, float beta) {
  float m = s * invn;
  float v = fmaf(q, invn, -m * m);
  float rstd = rsqrtf(v + BN_EPS);
  float a = gamma * rstd;
  float b = beta - m * a;
  return make_float2(a, b);
}

// round-to-nearest-even fp32 -> bf16
__device__ __forceinline__ unsigned short f2bf(float f) {
  unsigned u = __float_as_uint(f);
  u += 0x7FFFu + ((u >> 16) & 1u);
  return (unsigned short)(u >> 16);
}

// ---------------------------------------------------------------------------
// Stem conv: y1[N1][64] = gather(x, neigh) @ W  (fp32, K=108). Unchanged from
// round 0 (next round's target).
// ---------------------------------------------------------------------------
__global__ __launch_bounds__(256) void k_stem(
    const float* __restrict__ x, const int* __restrict__ neigh,
    const float* __restrict__ W, float* __restrict__ y1,
    float* __restrict__ stats) {
  constexpr int APAD = 116;
  __shared__ __align__(16) float Alds[64 * APAD];
  __shared__ __align__(16) float Blds[108 * 64];
  const int tid = threadIdx.x;
  const int n0 = blockIdx.x * 64;

  {
    const float4* Wf4 = (const float4*)W;
    float4* Bf4 = (float4*)Blds;
    for (int e = tid; e < 1728; e += 256) Bf4[e] = Wf4[e];
  }
  for (int j = 0; j < 7; ++j) {
    int g = tid + j * 256;
    if (g < 64 * 27) {
      int i = g / 27, k = g % 27;
      float4 v = make_float4(0.f, 0.f, 0.f, 0.f);
      int row = n0 + i;
      if (row < CN1) {
        int idx = neigh[row * 27 + k];
        v = *(const float4*)(x + idx * 4);
      }
      *(float4*)&Alds[i * APAD + k * 4] = v;
    }
  }
  __syncthreads();

  const int tc = tid & 15;
  const int tn = tid >> 4;
  float4 acc[4];
#pragma unroll
  for (int r = 0; r < 4; ++r) acc[r] = make_float4(0.f, 0.f, 0.f, 0.f);

#pragma unroll 3
  for (int kk4 = 0; kk4 < 27; ++kk4) {
    float4 a[4], b[4];
#pragma unroll
    for (int r = 0; r < 4; ++r)
      a[r] = *(const float4*)&Alds[(tn * 4 + r) * APAD + kk4 * 4];
#pragma unroll
    for (int q = 0; q < 4; ++q)
      b[q] = *(const float4*)&Blds[(kk4 * 4 + q) * 64 + tc * 4];
#pragma unroll
    for (int r = 0; r < 4; ++r) {
      fma4(acc[r], a[r].x, b[0]);
      fma4(acc[r], a[r].y, b[1]);
      fma4(acc[r], a[r].z, b[2]);
      fma4(acc[r], a[r].w, b[3]);
    }
  }

#pragma unroll
  for (int r = 0; r < 4; ++r) {
    int row = n0 + tn * 4 + r;
    if (row < CN1) *(float4*)&y1[row * 64 + tc * 4] = acc[r];
  }

  __syncthreads();
  float sx = 0, sy = 0, sz = 0, sw = 0, qx = 0, qy = 0, qz = 0, qw = 0;
#pragma unroll
  for (int r = 0; r < 4; ++r) {
    sx += acc[r].x; qx += acc[r].x * acc[r].x;
    sy += acc[r].y; qy += acc[r].y * acc[r].y;
    sz += acc[r].z; qz += acc[r].z * acc[r].z;
    sw += acc[r].w; qw += acc[r].w * acc[r].w;
  }
  float* S = Alds;
  float* Q = Alds + 16 * 64;
  S[tn * 64 + tc * 4 + 0] = sx; Q[tn * 64 + tc * 4 + 0] = qx;
  S[tn * 64 + tc * 4 + 1] = sy; Q[tn * 64 + tc * 4 + 1] = qy;
  S[tn * 64 + tc * 4 + 2] = sz; Q[tn * 64 + tc * 4 + 2] = qz;
  S[tn * 64 + tc * 4 + 3] = sw; Q[tn * 64 + tc * 4 + 3] = qw;
  __syncthreads();
  if (tid < 64) {
    float ss = 0.f, qq = 0.f;
#pragma unroll
    for (int t2 = 0; t2 < 16; ++t2) {
      ss += S[t2 * 64 + tid];
      qq += Q[t2 * 64 + tid];
    }
    atomicAdd(&stats[tid], ss);
    atomicAdd(&stats[64 + tid], qq);
  }
}

// ---------------------------------------------------------------------------
// Pool: h2[n][c] = relu(max_j BN(y1[child[n][j]][c])) -> bf16 output.
// ---------------------------------------------------------------------------
__global__ __launch_bounds__(256) void k_pool(
    const float* __restrict__ y1, const int* __restrict__ child,
    const float* __restrict__ stats, const float* __restrict__ gamma,
    const float* __restrict__ beta, unsigned short* __restrict__ h2) {
  const int tid = threadIdx.x;
  const int lane = tid & 63;
  const int n = blockIdx.x * 4 + (tid >> 6);
  float2 ab = bn_ab(stats[lane], stats[64 + lane], 1.0f / CN1, gamma[lane],
                    beta[lane]);
  float mx = -INFINITY, mn = INFINITY;
  const int* crow = child + n * 8;
#pragma unroll
  for (int j = 0; j < 8; ++j) {
    int ch = crow[j];
    float v = y1[ch * 64 + lane];
    mx = fmaxf(mx, v);
    mn = fminf(mn, v);
  }
  float t = (ab.x > 0.f) ? fmaf(ab.x, mx, ab.y) : fmaf(ab.x, mn, ab.y);
  h2[n * 64 + lane] = f2bf(fmaxf(t, 0.f));
}

// ---------------------------------------------------------------------------
// Weight prep: Wblk[k][d][cin] (bf16) from W[k][cin][d] (f32).
// Dual variant concatenates W1 (d 0..63) and Wd (d 64..127).
// ---------------------------------------------------------------------------
__global__ __launch_bounds__(256) void k_prep_dual(
    const float* __restrict__ W1, const float* __restrict__ Wd,
    unsigned short* __restrict__ Wdual) {
  int e = blockIdx.x * 256 + threadIdx.x;  // 27*128*64 = 221184
  if (e >= 27 * 128 * 64) return;
  int cin = e & 63, d = (e >> 6) & 127, k = e >> 13;
  float v = (d < 64) ? W1[(k * 64 + cin) * 64 + d]
                     : Wd[(k * 64 + cin) * 64 + (d - 64)];
  Wdual[e] = f2bf(v);
}

__global__ __launch_bounds__(256) void k_prep_res(
    const float* __restrict__ W2, unsigned short* __restrict__ Wres) {
  int e = blockIdx.x * 256 + threadIdx.x;  // 27*64*64 = 110592
  if (e >= 27 * 64 * 64) return;
  int cin = e & 63, d = (e >> 6) & 63, k = e >> 12;
  Wres[e] = f2bf(W2[(k * 64 + cin) * 64 + d]);
}

// ---------------------------------------------------------------------------
// MFMA gathered conv: out[M][OUTC] = gather(src,neigh) @ W, src bf16 [*][64],
// Wblk bf16 [27][OUTC][64] (pre-transposed). Block: 64 nodes x OUTC, 4 waves
// in 2x2 grid, wave tile 32 x OUTC/2, mfma_f32_16x16x32_bf16.
// XOR-swizzled LDS (T2), reg-prefetch staging one K-step ahead (T3-lite).
// Also accumulates per-channel sum/sumsq into stats[0..OUTC-1]/[OUTC..2*OUTC).
// ---------------------------------------------------------------------------
template <int OUTC>
__global__ __launch_bounds__(256) void k_mconv(
    const unsigned short* __restrict__ src, const int* __restrict__ neigh,
    const unsigned short* __restrict__ Wblk, float* __restrict__ out,
    float* __restrict__ stats, int M) {
  constexpr int NF = OUTC / 32;           // N-fragments per wave (2 or 4)
  constexpr int PPT = (OUTC * 128 / 16) / 256;  // B 16B-pieces per thread
  __shared__ __align__(16) unsigned char Ab[64 * 128];
  __shared__ __align__(16) unsigned char Bb[OUTC * 128];
  __shared__ int nlds[64 * 27];

  const int tid = threadIdx.x;
  const int n0 = blockIdx.x * 64;
  const int lane = tid & 63;
  const int w = tid >> 6;
  const int wm = w >> 1, wn = w & 1;
  const int gi = tid >> 2;   // gather node within tile
  const int gq = tid & 3;    // 32B quarter of a 128B row
  const int swA = (gi & 7) << 4;

  // neighbor tile -> LDS
  for (int e = tid; e < 64 * 27; e += 256) {
    int row = n0 + e / 27;
    nlds[e] = (row < M) ? neigh[row * 27 + e % 27] : -1;
  }

  f32x4 acc[2][NF] = {};

  uint4 rA0 = {}, rA1 = {};
  uint4 rB[PPT];

  __syncthreads();  // nlds ready

  // prologue: issue loads for k=0
  {
    int idx = nlds[gi * 27 + 0];
    if (idx >= 0) {
      const uint4* s = (const uint4*)(src + idx * 64 + gq * 16);
      rA0 = s[0]; rA1 = s[1];
    } else {
      rA0 = uint4{0, 0, 0, 0}; rA1 = uint4{0, 0, 0, 0};
    }
    const uint4* Bs = (const uint4*)(Wblk);
#pragma unroll
    for (int j = 0; j < PPT; ++j) rB[j] = Bs[tid * PPT + j];
  }

  for (int k = 0; k < 27; ++k) {
    // write staged regs to LDS (swizzled)
    *(uint4*)(Ab + gi * 128 + ((gq * 32) ^ swA)) = rA0;
    *(uint4*)(Ab + gi * 128 + ((gq * 32 + 16) ^ swA)) = rA1;
#pragma unroll
    for (int j = 0; j < PPT; ++j) {
      int p = tid * PPT + j;
      int d = p >> 3;
      int rb = (p & 7) * 16;
      *(uint4*)(Bb + d * 128 + (rb ^ ((d & 7) << 4))) = rB[j];
    }
    // issue next K-step's loads (latency hides under compute below)
    if (k < 26) {
      int idx = nlds[gi * 27 + k + 1];
      if (idx >= 0) {
        const uint4* s = (const uint4*)(src + idx * 64 + gq * 16);
        rA0 = s[0]; rA1 = s[1];
      } else {
        rA0 = uint4{0, 0, 0, 0}; rA1 = uint4{0, 0, 0, 0};
      }
      const uint4* Bs = (const uint4*)(Wblk + (k + 1) * OUTC * 64);
#pragma unroll
      for (int j = 0; j < PPT; ++j) rB[j] = Bs[tid * PPT + j];
    }
    __syncthreads();
    // compute: 2 sub-steps of K=32
#pragma unroll
    for (int ks = 0; ks < 2; ++ks) {
      int kb = ks * 64 + (lane >> 4) * 16;
      bf16x8 a[2];
#pragma unroll
      for (int mf = 0; mf < 2; ++mf) {
        int r = wm * 32 + mf * 16 + (lane & 15);
        a[mf] = *(const bf16x8*)(Ab + r * 128 + (kb ^ ((r & 7) << 4)));
      }
#pragma unroll
      for (int nf = 0; nf < NF; ++nf) {
        int d = wn * (OUTC / 2) + nf * 16 + (lane & 15);
        bf16x8 b = *(const bf16x8*)(Bb + d * 128 + (kb ^ ((d & 7) << 4)));
#pragma unroll
        for (int mf = 0; mf < 2; ++mf)
          acc[mf][nf] = __builtin_amdgcn_mfma_f32_16x16x32_bf16(
              a[mf], b, acc[mf][nf], 0, 0, 0);
      }
    }
    __syncthreads();
  }

  // epilogue: store. C/D layout: col=lane&15, row=(lane>>4)*4+reg.
#pragma unroll
  for (int mf = 0; mf < 2; ++mf) {
    int rbase = n0 + wm * 32 + mf * 16 + (lane >> 4) * 4;
#pragma unroll
    for (int nf = 0; nf < NF; ++nf) {
      int c = wn * (OUTC / 2) + nf * 16 + (lane & 15);
#pragma unroll
      for (int r = 0; r < 4; ++r) {
        int row = rbase + r;
        if (row < M) out[row * OUTC + c] = acc[mf][nf][r];
      }
    }
  }

  // stats: per-col sum/sumsq (invalid rows contributed zeros)
#pragma unroll
  for (int nf = 0; nf < NF; ++nf) {
    float s = 0.f, q = 0.f;
#pragma unroll
    for (int mf = 0; mf < 2; ++mf)
#pragma unroll
      for (int r = 0; r < 4; ++r) {
        float v = acc[mf][nf][r];
        s += v; q += v * v;
      }
    s += __shfl_xor(s, 16); s += __shfl_xor(s, 32);
    q += __shfl_xor(q, 16); q += __shfl_xor(q, 32);
    if (lane < 16) {
      int c = wn * (OUTC / 2) + nf * 16 + lane;
      atomicAdd(&stats[c], s);
      atomicAdd(&stats[OUTC + c], q);
    }
  }
}

// ---------------------------------------------------------------------------
// BN+ReLU on y2d channels 0..63 -> out1 (bf16)
// ---------------------------------------------------------------------------
__global__ __launch_bounds__(256) void k_bnrelu(
    const float* __restrict__ y2d, const float* __restrict__ stats,
    const float* __restrict__ gamma, const float* __restrict__ beta,
    unsigned short* __restrict__ out1) {
  int e = blockIdx.x * 256 + threadIdx.x;  // over N3*64 (exact)
  int i = e >> 6, c = e & 63;
  float2 ab = bn_ab(stats[c], stats[128 + c], 1.0f / CN3, gamma[c], beta[c]);
  out1[e] = f2bf(fmaxf(fmaf(ab.x, y2d[i * 128 + c], ab.y), 0.f));
}

// ---------------------------------------------------------------------------
// Final: relu(BN2(y3) + BNd(y2d[:,64:128]))
// ---------------------------------------------------------------------------
__global__ __launch_bounds__(256) void k_final(
    const float* __restrict__ y3, const float* __restrict__ y2d,
    const float* __restrict__ stats2, const float* __restrict__ stats1d,
    const float* __restrict__ g2, const float* __restrict__ b2,
    const float* __restrict__ gd, const float* __restrict__ bd,
    float* __restrict__ dout) {
  int e = blockIdx.x * 256 + threadIdx.x;  // over N3*64 (exact)
  int i = e >> 6, c = e & 63;
  float2 ab2 = bn_ab(stats2[c], stats2[64 + c], 1.0f / CN3, g2[c], b2[c]);
  float2 abd =
      bn_ab(stats1d[64 + c], stats1d[192 + c], 1.0f / CN3, gd[c], bd[c]);
  float o = fmaf(ab2.x, y3[e], ab2.y) + fmaf(abd.x, y2d[i * 128 + 64 + c], abd.y);
  dout[e] = fmaxf(o, 0.f);
}

// ---------------------------------------------------------------------------
extern "C" void kernel_launch(void* const* d_in, const int* in_sizes, int n_in,
                              void* d_out, int out_size, void* d_ws,
                              size_t ws_size, hipStream_t stream) {
  const float* x = (const float*)d_in[0];
  const int* neigh_stem = (const int*)d_in[1];
  const int* pool_child = (const int*)d_in[2];
  const int* neigh_ds = (const int*)d_in[3];
  const int* neigh_res = (const int*)d_in[4];
  const float* W_stem = (const float*)d_in[5];
  const float* g_stem = (const float*)d_in[6];
  const float* b_stem = (const float*)d_in[7];
  const float* W1 = (const float*)d_in[8];
  const float* g1 = (const float*)d_in[9];
  const float* b1 = (const float*)d_in[10];
  const float* W2 = (const float*)d_in[11];
  const float* g2 = (const float*)d_in[12];
  const float* b2 = (const float*)d_in[13];
  const float* Wd = (const float*)d_in[14];
  const float* gd = (const float*)d_in[15];
  const float* bd = (const float*)d_in[16];
  float* out = (float*)d_out;
  float* ws = (float*)d_ws;

  // Workspace (floats). y1 region reused for y2d/out1/y3 after pool.
  float* y1 = ws;                                   // 19,200,000 f32
  float* y2d = ws;                                  //  3,840,000 f32 (reuse)
  unsigned short* out1bf = (unsigned short*)(ws + 3840000);  // N3*64 bf16
  float* y3 = ws + 4800000;                         //  1,920,000 f32
  unsigned short* h2bf = (unsigned short*)(ws + 19200000);   // N2*64 bf16
  unsigned short* Wdual = (unsigned short*)(ws + 21760000);  // 27*128*64 bf16
  unsigned short* Wres = (unsigned short*)(ws + 21870592);   // 27*64*64 bf16
  float* stats = ws + 21925888;                     // 512 f32
  float* stats_stem = stats;                        // [128]
  float* stats_1d = stats + 128;                    // [256]
  float* stats_2 = stats + 384;                     // [128]

  hipMemsetAsync(stats, 0, 512 * sizeof(float), stream);

  k_prep_dual<<<(27 * 128 * 64 + 255) / 256, 256, 0, stream>>>(W1, Wd, Wdual);
  k_prep_res<<<(27 * 64 * 64 + 255) / 256, 256, 0, stream>>>(W2, Wres);

  k_stem<<<(CN1 + 63) / 64, 256, 0, stream>>>(x, neigh_stem, W_stem, y1,
                                              stats_stem);
  k_pool<<<CN2 / 4, 256, 0, stream>>>(y1, pool_child, stats_stem, g_stem,
                                      b_stem, h2bf);
  k_mconv<128><<<(CN3 + 63) / 64, 256, 0, stream>>>(h2bf, neigh_ds, Wdual,
                                                    y2d, stats_1d, CN3);
  k_bnrelu<<<CN3 * 64 / 256, 256, 0, stream>>>(y2d, stats_1d, g1, b1, out1bf);
  k_mconv<64><<<(CN3 + 63) / 64, 256, 0, stream>>>(out1bf, neigh_res, Wres,
                                                   y3, stats_2, CN3);
  k_final<<<CN3 * 64 / 256, 256, 0, stream>>>(y3, y2d, stats_2, stats_1d, g2,
                                              b2, gd, bd, out);
}